// Round 7
// baseline (2147.036 us; speedup 1.0000x reference)
//
#include <hip/hip_runtime.h>

// ---------------------------------------------------------------------------
// HeadsSelection: emb-gather -> 2x bidirectional LSTM -> additive attention
// S=256, B=16, V=20000, E=512, H=256, L=2, HM=128
// Round 14: producer/consumer wave split in k_lstm (R13's depth-2 poll
// regressed 597->701: doubled poll traffic added MALL queueing; reverted).
//   - Waves 4-7 stage ALL 4096 h entries (16 loads/lane, R12 sequential
//     poll); waves 0-3 never poll -> their serialized publish->poll leg
//     leaves the critical path; stager polling overlaps compute+publish.
//   - hL double-buffered by parity -> ONE barrier per step (stagers write
//     hL[(t+1)&1] while compute waves read hL[t&1]).
//   - A-row remap row = unit_off*4 + gate: MFMA C layout (row=quad*4+reg)
//     puts all 4 gates of one unit in one lane's acc[0..3] -> nonlinearity
//     fully in-register (Lg LDS + barrier2 deleted). Same K-order, same
//     3-product sums => h BIT-IDENTICAL to R12.
//   Exchange protocol (addresses, stamps, agent-scope stores) unchanged.
// ---------------------------------------------------------------------------

#define S_    256
#define B_    16
#define E_    512
#define H_    256
#define HM_   128
#define M_    4096   // S*B

typedef __attribute__((ext_vector_type(8))) short short8;
typedef __attribute__((ext_vector_type(4))) float f32x4;
union u32x4s8 { unsigned int u[4]; uint4 u4; short8 v; };

__device__ __forceinline__ float sigm(float x) { return 1.f / (1.f + __expf(-x)); }
__device__ __forceinline__ float tanh_fast(float x) {
  x = fminf(fmaxf(x, -15.f), 15.f);
  float e = __expf(2.f * x);
  return (e - 1.f) / (e + 1.f);
}
__device__ __forceinline__ unsigned short f2bf(float f) {
  unsigned u = __float_as_uint(f);
  u += 0x7FFFu + ((u >> 16) & 1u);
  return (unsigned short)(u >> 16);
}
__device__ __forceinline__ float bf2f(unsigned short s) {
  return __uint_as_float(((unsigned)s) << 16);
}
// pack float -> {low16: main bf16, high16: residual bf16}
__device__ __forceinline__ unsigned int packsplit(float f) {
  unsigned short m = f2bf(f);
  unsigned short r = f2bf(f - bf2f(m));
  return (unsigned)m | ((unsigned)r << 16);
}

// ---------------------------------------------------------------- gather ----
// gathers embedding rows and packs to split-bf16 u32 (consumed only by GEMM).
// every block zeroes 8 u64 of Hbuf (4096 x 8 = 32768 = both layers' stamps).
__global__ void k_gather_pk(const int* __restrict__ concepts, const float* __restrict__ emb,
                            unsigned int* __restrict__ Xpk,
                            unsigned long long* __restrict__ hbz) {
  if (threadIdx.x < 8)
    hbz[(size_t)blockIdx.x * 8 + threadIdx.x] = 0ull;
  int m = blockIdx.x;                       // m = s*16 + b
  int tok = concepts[m];
  const float4* src = reinterpret_cast<const float4*>(emb + (size_t)tok * E_);
  uint4* dst = reinterpret_cast<uint4*>(Xpk + (size_t)m * E_);
  for (int i = threadIdx.x; i < E_ / 4; i += blockDim.x) {
    float4 v = src[i];
    uint4 o;
    o.x = packsplit(v.x); o.y = packsplit(v.y); o.z = packsplit(v.z); o.w = packsplit(v.w);
    dst[i] = o;
  }
}

// ------------------------------------------------------------------ pack ----
__global__ void k_pack(const float* __restrict__ in, unsigned int* __restrict__ out, int n4) {
  int i = blockIdx.x * blockDim.x + threadIdx.x;
  if (i < n4) {
    float4 v = reinterpret_cast<const float4*>(in)[i];
    uint4 o;
    o.x = packsplit(v.x); o.y = packsplit(v.y); o.z = packsplit(v.z); o.w = packsplit(v.w);
    reinterpret_cast<uint4*>(out)[i] = o;
  }
}

// ------------------------------------------------------------- MFMA GEMM ----
// C[m][n] = sum_k A[m][k]*W[n][k] + bias[n], A/W packed split-bf16 u32.
// 3-product scheme: Am*Bm + Am*Br + Ar*Bm (~2^-17 rel err).
// WG = 128x128 tile, 4 waves in 2x2, wave = 64x64 (4x4 MFMA 16x16x32 tiles).
__global__ __launch_bounds__(256) void k_gemm_pk(const unsigned int* __restrict__ Apk,
                                                 const unsigned int* __restrict__ Wpk,
                                                 const float* __restrict__ bias,
                                                 float* __restrict__ C, int N, int K) {
  __shared__ unsigned int As[128][36];
  __shared__ unsigned int Ws2[128][36];
  const int bm = blockIdx.x * 128, bn = blockIdx.y * 128;
  const int tid = threadIdx.x;
  const int wave = tid >> 6, lane = tid & 63;
  const int wm = (wave >> 1) << 6, wn = (wave & 1) << 6;
  const int l16 = lane & 15, quad = lane >> 4;
  const int r = tid >> 1, cb = (tid & 1) << 4;

  f32x4 acc[4][4];
#pragma unroll
  for (int i = 0; i < 4; ++i)
#pragma unroll
    for (int j = 0; j < 4; ++j) acc[i][j] = (f32x4){0.f, 0.f, 0.f, 0.f};

  for (int k0 = 0; k0 < K; k0 += 32) {
    const unsigned int* pa = Apk + (size_t)(bm + r) * K + k0 + cb;
    const unsigned int* pw = Wpk + (size_t)(bn + r) * K + k0 + cb;
    uint4 a0 = *(const uint4*)pa, a1 = *(const uint4*)(pa + 4),
          a2 = *(const uint4*)(pa + 8), a3 = *(const uint4*)(pa + 12);
    uint4 w0 = *(const uint4*)pw, w1 = *(const uint4*)(pw + 4),
          w2 = *(const uint4*)(pw + 8), w3 = *(const uint4*)(pw + 12);
    __syncthreads();                         // previous iter's frag reads done
    *(uint4*)&As[r][cb] = a0;  *(uint4*)&As[r][cb + 4] = a1;
    *(uint4*)&As[r][cb + 8] = a2; *(uint4*)&As[r][cb + 12] = a3;
    *(uint4*)&Ws2[r][cb] = w0; *(uint4*)&Ws2[r][cb + 4] = w1;
    *(uint4*)&Ws2[r][cb + 8] = w2; *(uint4*)&Ws2[r][cb + 12] = w3;
    __syncthreads();

    short8 Amv[4], Arv[4], Bmv[4], Brv[4];
#pragma unroll
    for (int t = 0; t < 4; ++t) {
      const unsigned int* p = &As[wm + (t << 4) + l16][quad << 3];
      uint4 p0 = *(const uint4*)p, p1 = *(const uint4*)(p + 4);
      u32x4s8 m, rr;
      m.u[0] = __builtin_amdgcn_perm(p0.y, p0.x, 0x05040100u);
      rr.u[0] = __builtin_amdgcn_perm(p0.y, p0.x, 0x07060302u);
      m.u[1] = __builtin_amdgcn_perm(p0.w, p0.z, 0x05040100u);
      rr.u[1] = __builtin_amdgcn_perm(p0.w, p0.z, 0x07060302u);
      m.u[2] = __builtin_amdgcn_perm(p1.y, p1.x, 0x05040100u);
      rr.u[2] = __builtin_amdgcn_perm(p1.y, p1.x, 0x07060302u);
      m.u[3] = __builtin_amdgcn_perm(p1.w, p1.z, 0x05040100u);
      rr.u[3] = __builtin_amdgcn_perm(p1.w, p1.z, 0x07060302u);
      Amv[t] = m.v; Arv[t] = rr.v;
      const unsigned int* pb = &Ws2[wn + (t << 4) + l16][quad << 3];
      uint4 q0 = *(const uint4*)pb, q1 = *(const uint4*)(pb + 4);
      m.u[0] = __builtin_amdgcn_perm(q0.y, q0.x, 0x05040100u);
      rr.u[0] = __builtin_amdgcn_perm(q0.y, q0.x, 0x07060302u);
      m.u[1] = __builtin_amdgcn_perm(q0.w, q0.z, 0x05040100u);
      rr.u[1] = __builtin_amdgcn_perm(q0.w, q0.z, 0x07060302u);
      m.u[2] = __builtin_amdgcn_perm(q1.y, q1.x, 0x05040100u);
      rr.u[2] = __builtin_amdgcn_perm(q1.y, q1.x, 0x07060302u);
      m.u[3] = __builtin_amdgcn_perm(q1.w, q1.z, 0x05040100u);
      rr.u[3] = __builtin_amdgcn_perm(q1.w, q1.z, 0x07060302u);
      Bmv[t] = m.v; Brv[t] = rr.v;
    }
#pragma unroll
    for (int ti = 0; ti < 4; ++ti)
#pragma unroll
      for (int tj = 0; tj < 4; ++tj) {
        acc[ti][tj] = __builtin_amdgcn_mfma_f32_16x16x32_bf16(Amv[ti], Bmv[tj], acc[ti][tj], 0, 0, 0);
        acc[ti][tj] = __builtin_amdgcn_mfma_f32_16x16x32_bf16(Amv[ti], Brv[tj], acc[ti][tj], 0, 0, 0);
        acc[ti][tj] = __builtin_amdgcn_mfma_f32_16x16x32_bf16(Arv[ti], Bmv[tj], acc[ti][tj], 0, 0, 0);
      }
  }

  float bv[4];
#pragma unroll
  for (int tj = 0; tj < 4; ++tj)
    bv[tj] = bias ? bias[bn + wn + (tj << 4) + l16] : 0.f;
#pragma unroll
  for (int ti = 0; ti < 4; ++ti)
#pragma unroll
    for (int rr = 0; rr < 4; ++rr) {
      float* crow = C + (size_t)(bm + wm + (ti << 4) + (quad << 2) + rr) * N + bn + wn + l16;
      crow[0]  = acc[ti][0][rr] + bv[0];
      crow[16] = acc[ti][1][rr] + bv[1];
      crow[32] = acc[ti][2][rr] + bv[2];
      crow[48] = acc[ti][3][rr] + bv[3];
    }
}

// ------------------------------------------------------------- fp32 GEMM ----
// merged projections: blockIdx.y==0 -> C0 = A @ W0^T (Ua->Pm),
//                     blockIdx.y==1 -> C1 = A @ W1^T (Wa->Cm).
__global__ __launch_bounds__(256) void k_gemm2(const float* __restrict__ A,
                                               const float* __restrict__ W0,
                                               const float* __restrict__ W1,
                                               float* __restrict__ C0,
                                               float* __restrict__ C1,
                                               int N, int K) {
  __shared__ __align__(16) float As[16][132];
  __shared__ __align__(16) float Ws[16][132];
  const float* W = blockIdx.y ? W1 : W0;
  float* C = blockIdx.y ? C1 : C0;
  const int bm = blockIdx.x * 128;
  const int tid = threadIdx.x;
  const int tm = (tid >> 4) * 8, tn = (tid & 15) * 8;
  float acc[8][8];
#pragma unroll
  for (int i = 0; i < 8; i++)
#pragma unroll
    for (int j = 0; j < 8; j++) acc[i][j] = 0.f;

  const int lr = tid >> 1, lk = (tid & 1) * 8;
  for (int k0 = 0; k0 < K; k0 += 16) {
    float4 a0 = *(const float4*)(A + (size_t)(bm + lr) * K + k0 + lk);
    float4 a1 = *(const float4*)(A + (size_t)(bm + lr) * K + k0 + lk + 4);
    float4 w0 = *(const float4*)(W + (size_t)(lr) * K + k0 + lk);
    float4 w1 = *(const float4*)(W + (size_t)(lr) * K + k0 + lk + 4);
    As[lk + 0][lr] = a0.x; As[lk + 1][lr] = a0.y; As[lk + 2][lr] = a0.z; As[lk + 3][lr] = a0.w;
    As[lk + 4][lr] = a1.x; As[lk + 5][lr] = a1.y; As[lk + 6][lr] = a1.z; As[lk + 7][lr] = a1.w;
    Ws[lk + 0][lr] = w0.x; Ws[lk + 1][lr] = w0.y; Ws[lk + 2][lr] = w0.z; Ws[lk + 3][lr] = w0.w;
    Ws[lk + 4][lr] = w1.x; Ws[lk + 5][lr] = w1.y; Ws[lk + 6][lr] = w1.z; Ws[lk + 7][lr] = w1.w;
    __syncthreads();
#pragma unroll
    for (int k = 0; k < 16; k++) {
      float4 av0 = *(const float4*)&As[k][tm];
      float4 av1 = *(const float4*)&As[k][tm + 4];
      float4 wv0 = *(const float4*)&Ws[k][tn];
      float4 wv1 = *(const float4*)&Ws[k][tn + 4];
      float a[8] = {av0.x, av0.y, av0.z, av0.w, av1.x, av1.y, av1.z, av1.w};
      float w[8] = {wv0.x, wv0.y, wv0.z, wv0.w, wv1.x, wv1.y, wv1.z, wv1.w};
#pragma unroll
      for (int i = 0; i < 8; i++)
#pragma unroll
        for (int j = 0; j < 8; j++) acc[i][j] += a[i] * w[j];
    }
    __syncthreads();
  }

#pragma unroll
  for (int i = 0; i < 8; i++) {
    float4 v0 = make_float4(acc[i][0], acc[i][1], acc[i][2], acc[i][3]);
    float4 v1 = make_float4(acc[i][4], acc[i][5], acc[i][6], acc[i][7]);
    *(float4*)(C + (size_t)(bm + tm + i) * N + tn) = v0;
    *(float4*)(C + (size_t)(bm + tm + i) * N + tn + 4) = v1;
  }
}

// ------------------------------------------------------------- LSTM layer ----
// Grid: 32 WGs = dir(2) x g(16), 512 threads (8 waves).
// Waves 0-3 (compute): MFMA + in-register nonlin + publish. A-rows are
//   unit-major (row = uoff*4 + gate), so C layout (row=quad*4+reg) gives
//   lane (quad,bcol) the 4 gates of unit g*16+w8*4+quad, batch bcol, in
//   acc[0..3]. No Lg LDS, no second barrier. Lane also owns c_reg.
// Waves 4-7 (stagers): sequential-poll ALL 4096 h entries (16/lane) from
//   Hbuf (R12/R4 MALL protocol, stamp-validated), write hL[(it)&1].
// hL double-buffered by parity -> one barrier per step.
// Hbuf entries: u64 {stamp=it+1, packed h}; relaxed agent-scope store.
__global__ __launch_bounds__(512) void k_lstm(const float* __restrict__ Gin,
                                              const float* __restrict__ whh,
                                              float* __restrict__ Houtf,
                                              unsigned int* __restrict__ Houtp,
                                              unsigned long long* __restrict__ Hbuf) {
  const int d = blockIdx.x >> 4;
  const int g = blockIdx.x & 15;
  const int tid = threadIdx.x;
  const int w8 = tid >> 6;         // waves 0-3 compute, 4-7 stage
  const int lane = tid & 63;
  const int bcol = lane & 15;      // batch (MFMA A/C row-sel and C col)
  const int quad = lane >> 4;
  __shared__ unsigned int hL[2][16 * 260];        // [parity][b*260 + k]

  // ---- one-time (waves 0-3): A fragments, unit-major rows ----
  // A row r = bcol: unit_off = r>>2, gate = r&3
  // whh row = d*1024 + gate*256 + (g*16 + w8*4 + unit_off)
  unsigned int Am[8][4], Ar[8][4];
  if (w8 < 4) {
    const float* wrow = whh + (size_t)((d << 10) + ((bcol & 3) << 8) + (g << 4) +
                                       (w8 << 2) + (bcol >> 2)) * 256;
#pragma unroll
    for (int s = 0; s < 8; ++s) {
      float w[8];
      *(float4*)&w[0] = *(const float4*)(wrow + s * 32 + quad * 8);
      *(float4*)&w[4] = *(const float4*)(wrow + s * 32 + quad * 8 + 4);
#pragma unroll
      for (int j = 0; j < 4; ++j) {
        unsigned short m0 = f2bf(w[2 * j]), m1 = f2bf(w[2 * j + 1]);
        unsigned short r0 = f2bf(w[2 * j] - bf2f(m0));
        unsigned short r1 = f2bf(w[2 * j + 1] - bf2f(m1));
        Am[s][j] = (unsigned)m0 | ((unsigned)m1 << 16);
        Ar[s][j] = (unsigned)r0 | ((unsigned)r1 << 16);
      }
    }
  }
  const int sw = w8 - 4;           // stager wave index 0..3
  float c_reg = 0.f;

  for (int it = 0; it < 256; ++it) {
    const int step = d ? (255 - it) : it;

    // ---- stagers: poll ALL entries (b=c, k=sw*64+lane), write hL[it&1] ----
    if (w8 >= 4 && it > 0) {
      const unsigned long long* src = Hbuf + ((size_t)((d << 1) + ((it - 1) & 1)) << 12);
      const unsigned long long* p0 = src + (sw << 6) + lane;   // + c*256
      const unsigned int want = (unsigned int)it;
      unsigned long long v[16];
#pragma unroll
      for (int c = 0; c < 16; ++c)
        v[c] = __hip_atomic_load(p0 + (c << 8), __ATOMIC_RELAXED, __HIP_MEMORY_SCOPE_AGENT);
      for (;;) {
        unsigned int badm = 0;
#pragma unroll
        for (int c = 0; c < 16; ++c)
          badm |= ((unsigned int)(v[c] >> 32) != want) ? (1u << c) : 0u;
        if (__ballot(badm != 0) == 0ull) break;
#pragma unroll
        for (int c = 0; c < 16; ++c)
          if (badm & (1u << c))
            v[c] = __hip_atomic_load(p0 + (c << 8), __ATOMIC_RELAXED, __HIP_MEMORY_SCOPE_AGENT);
      }
      unsigned int* hdst = &hL[it & 1][(sw << 6) + lane];
#pragma unroll
      for (int c = 0; c < 16; ++c)
        hdst[c * 260] = (unsigned int)v[c];    // hL[p][c*260 + sw*64+lane]
    }
    __syncthreads();

    // ---- compute waves: gin prefetch, MFMA, in-register nonlin, publish ----
    if (w8 < 4) {
      // lane (quad,bcol) owns unit u = g*16 + w8*4 + quad, batch bcol
      float gin[4];
#pragma unroll
      for (int qq = 0; qq < 4; ++qq)
        gin[qq] = Gin[((size_t)((step << 4) + bcol) << 11) + (d << 10) + (qq << 8) +
                      (g << 4) + (w8 << 2) + quad];

      f32x4 acc0 = {0.f, 0.f, 0.f, 0.f}, acc1 = acc0, acc2 = acc0;
      if (it > 0) {
        const unsigned int* hrow = &hL[it & 1][bcol * 260];
#pragma unroll
        for (int s = 0; s < 8; ++s) {
          const unsigned int* p = hrow + (s << 5) + (quad << 3);
          uint4 p0v = *(const uint4*)p;
          uint4 p1v = *(const uint4*)(p + 4);
          u32x4s8 Bm, Br, Amu, Aru;
          Bm.u[0] = __builtin_amdgcn_perm(p0v.y, p0v.x, 0x05040100u);
          Br.u[0] = __builtin_amdgcn_perm(p0v.y, p0v.x, 0x07060302u);
          Bm.u[1] = __builtin_amdgcn_perm(p0v.w, p0v.z, 0x05040100u);
          Br.u[1] = __builtin_amdgcn_perm(p0v.w, p0v.z, 0x07060302u);
          Bm.u[2] = __builtin_amdgcn_perm(p1v.y, p1v.x, 0x05040100u);
          Br.u[2] = __builtin_amdgcn_perm(p1v.y, p1v.x, 0x07060302u);
          Bm.u[3] = __builtin_amdgcn_perm(p1v.w, p1v.z, 0x05040100u);
          Br.u[3] = __builtin_amdgcn_perm(p1v.w, p1v.z, 0x07060302u);
#pragma unroll
          for (int j = 0; j < 4; ++j) { Amu.u[j] = Am[s][j]; Aru.u[j] = Ar[s][j]; }
          acc0 = __builtin_amdgcn_mfma_f32_16x16x32_bf16(Amu.v, Bm.v, acc0, 0, 0, 0);
          acc1 = __builtin_amdgcn_mfma_f32_16x16x32_bf16(Amu.v, Br.v, acc1, 0, 0, 0);
          acc2 = __builtin_amdgcn_mfma_f32_16x16x32_bf16(Aru.v, Bm.v, acc2, 0, 0, 0);
        }
      }
      f32x4 t = acc0 + acc1 + acc2;   // t[j] = gate j of (unit, batch)

      float gi = t[0] + gin[0];
      float gf = t[1] + gin[1];
      float gg = t[2] + gin[2];
      float go = t[3] + gin[3];
      float ct = sigm(gf) * c_reg + sigm(gi) * tanh_fast(gg);
      c_reg = ct;
      float h = sigm(go) * tanh_fast(ct);
      unsigned short hm = f2bf(h);
      unsigned short hr = f2bf(h - bf2f(hm));
      unsigned int hpk = ((unsigned)hr << 16) | (unsigned)hm;
      unsigned long long hp = ((unsigned long long)(unsigned int)(it + 1) << 32) |
                              (unsigned long long)hpk;
      __hip_atomic_store(Hbuf + ((size_t)((d << 1) + (it & 1)) << 12) +
                         (bcol << 8) + (g << 4) + (w8 << 2) + quad,
                         hp, __ATOMIC_RELAXED, __HIP_MEMORY_SCOPE_AGENT);
      size_t oidx = (size_t)((step << 4) + bcol) * 512 + (d << 8) + (g << 4) +
                    (w8 << 2) + quad;
      Houtf[oidx] = h;
      Houtp[oidx] = hpk;
    }
    // no drain barrier: stagers validate stamps themselves.
  }
}

// ------------------------------------------------------------- attention ----
// scores[b][i][j] = sum_h va[h]*tanh(P[i*16+b][h] + Cc[j*16+b][h])
// out[0 .. 1M) = scores; out[1M .. 2M) = predictions (sigmoid>=0.5 <=> x>=0)
__global__ __launch_bounds__(256) void k_attn(const float* __restrict__ P,
                                              const float* __restrict__ Cc,
                                              const float* __restrict__ va,
                                              float* __restrict__ out) {
  const int b = blockIdx.x & 15, i = blockIdx.x >> 4;
  __shared__ float pv[128], vv[128];
  const int t = threadIdx.x;
  if (t < 128) {
    pv[t] = P[(size_t)((i << 4) + b) * 128 + t];
    vv[t] = va[t];
  }
  __syncthreads();
  const float4* c4 = reinterpret_cast<const float4*>(Cc + (size_t)((t << 4) + b) * 128);
  float acc = 0.f;
#pragma unroll 8
  for (int hh = 0; hh < 32; ++hh) {
    float4 cv = c4[hh];
    int h = hh << 2;
    acc += vv[h]     * tanh_fast(pv[h]     + cv.x);
    acc += vv[h + 1] * tanh_fast(pv[h + 1] + cv.y);
    acc += vv[h + 2] * tanh_fast(pv[h + 2] + cv.z);
    acc += vv[h + 3] * tanh_fast(pv[h + 3] + cv.w);
  }
  size_t o = ((size_t)b << 16) + ((size_t)i << 8) + (size_t)t;
  out[o] = acc;
  out[(1u << 20) + o] = (acc >= 0.f) ? 1.f : 0.f;
}

// --------------------------------------------------------------- launch ----
extern "C" void kernel_launch(void* const* d_in, const int* in_sizes, int n_in,
                              void* d_out, int out_size, void* d_ws, size_t ws_size,
                              hipStream_t stream) {
  const int*   concepts = (const int*)d_in[0];
  // d_in[1] = concepts_lengths (all == S, unused)
  const float* emb  = (const float*)d_in[2];
  const float* w_ih = (const float*)d_in[3];   // [2][2][1024][512]
  const float* w_hh = (const float*)d_in[4];   // [2][2][1024][256]
  const float* bias = (const float*)d_in[5];   // [2][2][1024]
  const float* Ua   = (const float*)d_in[6];   // [128][512]
  const float* Wa   = (const float*)d_in[7];   // [128][512]
  const float* va   = (const float*)d_in[8];   // [1][128]
  float* out = (float*)d_out;
  float* ws  = (float*)d_ws;

  // workspace (floats) — total 15,794,176 floats = byte-identical to R4 usage
  constexpr size_t OFF_G   = 0;                               // [4096][2048] f32
  constexpr size_t OFF_PK  = OFF_G  + (size_t)M_ * 2048;      // Xpk/H0pk/H1pk u32 [4096][512]
  constexpr size_t OFF_WPK = OFF_PK + (size_t)M_ * 512;       // Wpk u32 [2][2048][512]
  constexpr size_t OFF_HF  = OFF_WPK + 2 * 2048 * 512;        // H f32 [4096][512]
  constexpr size_t OFF_P   = OFF_HF + (size_t)M_ * 512;       // Pm [4096][128]
  constexpr size_t OFF_C   = OFF_P  + (size_t)M_ * HM_;       // Cm [4096][128]
  constexpr size_t OFF_HB  = OFF_C  + (size_t)M_ * HM_;       // Hbuf u64 x2 layers

  float* G  = ws + OFF_G;
  unsigned int* PK  = (unsigned int*)(ws + OFF_PK);
  unsigned int* WPK = (unsigned int*)(ws + OFF_WPK);
  float* HF = ws + OFF_HF;
  float* Pm = ws + OFF_P;
  float* Cm = ws + OFF_C;
  unsigned long long* Hb0 = (unsigned long long*)(ws + OFF_HB);
  unsigned long long* Hb1 = Hb0 + 2 * 2 * 4096;

  // pack w_ih (both layers) once; gather packs X directly
  // (k_gather_pk also zeroes all Hbuf stamps each replay)
  k_pack<<<(2 * 2048 * 512 / 4 + 255) / 256, 256, 0, stream>>>(w_ih, WPK, 2 * 2048 * 512 / 4);
  k_gather_pk<<<M_, 128, 0, stream>>>(concepts, emb, PK, Hb0);

  // layer 0: Gin GEMM (MFMA split-bf16) then recurrence (writes H0 packed into PK)
  k_gemm_pk<<<dim3(32, 16), 256, 0, stream>>>(PK, WPK, bias, G, 2048, 512);
  k_lstm<<<32, 512, 0, stream>>>(G, w_hh, HF, PK, Hb0);   // PK now = H0pk (Xpk dead)

  // layer 1
  k_gemm_pk<<<dim3(32, 16), 256, 0, stream>>>(PK, WPK + (size_t)2048 * 512, bias + 2048,
                                              G, 2048, 512);
  k_lstm<<<32, 512, 0, stream>>>(G, w_hh + (size_t)2048 * 256, HF, PK, Hb1);  // HF = H1 f32

  // attention projections (fp32; small) — both in ONE launch, bit-identical
  // per-block arithmetic to the previous two back-to-back k_gemm calls.
  k_gemm2<<<dim3(32, 2), 256, 0, stream>>>(HF, Ua, Wa, Pm, Cm, HM_, 512);

  // fused pairwise scores + predictions
  k_attn<<<M_, 256, 0, stream>>>(Pm, Cm, va, out);
}

// Round 8
// 1822.696 us; speedup vs baseline: 1.1779x; 1.1779x over previous
//
#include <hip/hip_runtime.h>

// ---------------------------------------------------------------------------
// HeadsSelection: emb-gather -> 2x bidirectional LSTM -> additive attention
// S=256, B=16, V=20000, E=512, H=256, L=2, HM=128
// Round 15: controlled hybrid of R12 (best, 1491us) and R14.
//   R14 post-mortem: 965us/layer regression came with FETCH +32MB -> blame
//   the polling restructure (no rotation, 4 waves x 16 loads), NOT the math
//   remap or barrier structure. This round isolates:
//   - staging/poll: R12 VERBATIM (8 waves x 8 entries, g-rotated, MALL
//     protocol) — the config that measured 597us/layer.
//   - compute: R14's unit-major A-rows (gates of one unit in one lane's
//     acc[0..3]) -> in-register nonlin, Lg LDS deleted.
//   - hL parity double-buffer -> ONE barrier per step (writes hL[it&1],
//     reads hL[it&1] between the same barriers; stage(it+2) can't touch
//     hL[it&1] until barrier(it+1) passed = all reads done).
//   h values bit-identical to R12/R14 (same dots, same order; both passed).
//   Also: k_pack + k_gather_pk fused into one launch (saves a launch gap).
// ---------------------------------------------------------------------------

#define S_    256
#define B_    16
#define E_    512
#define H_    256
#define HM_   128
#define M_    4096   // S*B

typedef __attribute__((ext_vector_type(8))) short short8;
typedef __attribute__((ext_vector_type(4))) float f32x4;
union u32x4s8 { unsigned int u[4]; uint4 u4; short8 v; };

__device__ __forceinline__ float sigm(float x) { return 1.f / (1.f + __expf(-x)); }
__device__ __forceinline__ float tanh_fast(float x) {
  x = fminf(fmaxf(x, -15.f), 15.f);
  float e = __expf(2.f * x);
  return (e - 1.f) / (e + 1.f);
}
__device__ __forceinline__ unsigned short f2bf(float f) {
  unsigned u = __float_as_uint(f);
  u += 0x7FFFu + ((u >> 16) & 1u);
  return (unsigned short)(u >> 16);
}
__device__ __forceinline__ float bf2f(unsigned short s) {
  return __uint_as_float(((unsigned)s) << 16);
}
// pack float -> {low16: main bf16, high16: residual bf16}
__device__ __forceinline__ unsigned int packsplit(float f) {
  unsigned short m = f2bf(f);
  unsigned short r = f2bf(f - bf2f(m));
  return (unsigned)m | ((unsigned)r << 16);
}

// ----------------------------------------------------- fused pack+gather ----
// blocks [0, npack): pack w_ih float->split-bf16 u32 (4 floats/thread).
// blocks [npack, npack+4096): gather emb rows -> Xpk packed; also zero the
// Hbuf stamp region (4096 blocks x 8 u64 = both layers' stamps).
__global__ void k_prep(const float* __restrict__ w_ih, unsigned int* __restrict__ WPK,
                       int n4, int npack,
                       const int* __restrict__ concepts, const float* __restrict__ emb,
                       unsigned int* __restrict__ Xpk,
                       unsigned long long* __restrict__ hbz) {
  if (blockIdx.x < (unsigned)npack) {
    int i = blockIdx.x * blockDim.x + threadIdx.x;
    if (i < n4) {
      float4 v = reinterpret_cast<const float4*>(w_ih)[i];
      uint4 o;
      o.x = packsplit(v.x); o.y = packsplit(v.y); o.z = packsplit(v.z); o.w = packsplit(v.w);
      reinterpret_cast<uint4*>(WPK)[i] = o;
    }
    return;
  }
  int m = blockIdx.x - npack;               // m = s*16 + b
  if (threadIdx.x < 8)
    hbz[(size_t)m * 8 + threadIdx.x] = 0ull;
  int tok = concepts[m];
  const float4* src = reinterpret_cast<const float4*>(emb + (size_t)tok * E_);
  uint4* dst = reinterpret_cast<uint4*>(Xpk + (size_t)m * E_);
  for (int i = threadIdx.x; i < E_ / 4; i += blockDim.x) {
    float4 v = src[i];
    uint4 o;
    o.x = packsplit(v.x); o.y = packsplit(v.y); o.z = packsplit(v.z); o.w = packsplit(v.w);
    dst[i] = o;
  }
}

// ------------------------------------------------------------- MFMA GEMM ----
// C[m][n] = sum_k A[m][k]*W[n][k] + bias[n], A/W packed split-bf16 u32.
// 3-product scheme: Am*Bm + Am*Br + Ar*Bm (~2^-17 rel err).
// WG = 128x128 tile, 4 waves in 2x2, wave = 64x64 (4x4 MFMA 16x16x32 tiles).
__global__ __launch_bounds__(256) void k_gemm_pk(const unsigned int* __restrict__ Apk,
                                                 const unsigned int* __restrict__ Wpk,
                                                 const float* __restrict__ bias,
                                                 float* __restrict__ C, int N, int K) {
  __shared__ unsigned int As[128][36];
  __shared__ unsigned int Ws2[128][36];
  const int bm = blockIdx.x * 128, bn = blockIdx.y * 128;
  const int tid = threadIdx.x;
  const int wave = tid >> 6, lane = tid & 63;
  const int wm = (wave >> 1) << 6, wn = (wave & 1) << 6;
  const int l16 = lane & 15, quad = lane >> 4;
  const int r = tid >> 1, cb = (tid & 1) << 4;

  f32x4 acc[4][4];
#pragma unroll
  for (int i = 0; i < 4; ++i)
#pragma unroll
    for (int j = 0; j < 4; ++j) acc[i][j] = (f32x4){0.f, 0.f, 0.f, 0.f};

  for (int k0 = 0; k0 < K; k0 += 32) {
    const unsigned int* pa = Apk + (size_t)(bm + r) * K + k0 + cb;
    const unsigned int* pw = Wpk + (size_t)(bn + r) * K + k0 + cb;
    uint4 a0 = *(const uint4*)pa, a1 = *(const uint4*)(pa + 4),
          a2 = *(const uint4*)(pa + 8), a3 = *(const uint4*)(pa + 12);
    uint4 w0 = *(const uint4*)pw, w1 = *(const uint4*)(pw + 4),
          w2 = *(const uint4*)(pw + 8), w3 = *(const uint4*)(pw + 12);
    __syncthreads();                         // previous iter's frag reads done
    *(uint4*)&As[r][cb] = a0;  *(uint4*)&As[r][cb + 4] = a1;
    *(uint4*)&As[r][cb + 8] = a2; *(uint4*)&As[r][cb + 12] = a3;
    *(uint4*)&Ws2[r][cb] = w0; *(uint4*)&Ws2[r][cb + 4] = w1;
    *(uint4*)&Ws2[r][cb + 8] = w2; *(uint4*)&Ws2[r][cb + 12] = w3;
    __syncthreads();

    short8 Amv[4], Arv[4], Bmv[4], Brv[4];
#pragma unroll
    for (int t = 0; t < 4; ++t) {
      const unsigned int* p = &As[wm + (t << 4) + l16][quad << 3];
      uint4 p0 = *(const uint4*)p, p1 = *(const uint4*)(p + 4);
      u32x4s8 m, rr;
      m.u[0] = __builtin_amdgcn_perm(p0.y, p0.x, 0x05040100u);
      rr.u[0] = __builtin_amdgcn_perm(p0.y, p0.x, 0x07060302u);
      m.u[1] = __builtin_amdgcn_perm(p0.w, p0.z, 0x05040100u);
      rr.u[1] = __builtin_amdgcn_perm(p0.w, p0.z, 0x07060302u);
      m.u[2] = __builtin_amdgcn_perm(p1.y, p1.x, 0x05040100u);
      rr.u[2] = __builtin_amdgcn_perm(p1.y, p1.x, 0x07060302u);
      m.u[3] = __builtin_amdgcn_perm(p1.w, p1.z, 0x05040100u);
      rr.u[3] = __builtin_amdgcn_perm(p1.w, p1.z, 0x07060302u);
      Amv[t] = m.v; Arv[t] = rr.v;
      const unsigned int* pb = &Ws2[wn + (t << 4) + l16][quad << 3];
      uint4 q0 = *(const uint4*)pb, q1 = *(const uint4*)(pb + 4);
      m.u[0] = __builtin_amdgcn_perm(q0.y, q0.x, 0x05040100u);
      rr.u[0] = __builtin_amdgcn_perm(q0.y, q0.x, 0x07060302u);
      m.u[1] = __builtin_amdgcn_perm(q0.w, q0.z, 0x05040100u);
      rr.u[1] = __builtin_amdgcn_perm(q0.w, q0.z, 0x07060302u);
      m.u[2] = __builtin_amdgcn_perm(q1.y, q1.x, 0x05040100u);
      rr.u[2] = __builtin_amdgcn_perm(q1.y, q1.x, 0x07060302u);
      m.u[3] = __builtin_amdgcn_perm(q1.w, q1.z, 0x05040100u);
      rr.u[3] = __builtin_amdgcn_perm(q1.w, q1.z, 0x07060302u);
      Bmv[t] = m.v; Brv[t] = rr.v;
    }
#pragma unroll
    for (int ti = 0; ti < 4; ++ti)
#pragma unroll
      for (int tj = 0; tj < 4; ++tj) {
        acc[ti][tj] = __builtin_amdgcn_mfma_f32_16x16x32_bf16(Amv[ti], Bmv[tj], acc[ti][tj], 0, 0, 0);
        acc[ti][tj] = __builtin_amdgcn_mfma_f32_16x16x32_bf16(Amv[ti], Brv[tj], acc[ti][tj], 0, 0, 0);
        acc[ti][tj] = __builtin_amdgcn_mfma_f32_16x16x32_bf16(Arv[ti], Bmv[tj], acc[ti][tj], 0, 0, 0);
      }
  }

  float bv[4];
#pragma unroll
  for (int tj = 0; tj < 4; ++tj)
    bv[tj] = bias ? bias[bn + wn + (tj << 4) + l16] : 0.f;
#pragma unroll
  for (int ti = 0; ti < 4; ++ti)
#pragma unroll
    for (int rr = 0; rr < 4; ++rr) {
      float* crow = C + (size_t)(bm + wm + (ti << 4) + (quad << 2) + rr) * N + bn + wn + l16;
      crow[0]  = acc[ti][0][rr] + bv[0];
      crow[16] = acc[ti][1][rr] + bv[1];
      crow[32] = acc[ti][2][rr] + bv[2];
      crow[48] = acc[ti][3][rr] + bv[3];
    }
}

// ------------------------------------------------------------- fp32 GEMM ----
// merged projections: blockIdx.y==0 -> C0 = A @ W0^T (Ua->Pm),
//                     blockIdx.y==1 -> C1 = A @ W1^T (Wa->Cm).
__global__ __launch_bounds__(256) void k_gemm2(const float* __restrict__ A,
                                               const float* __restrict__ W0,
                                               const float* __restrict__ W1,
                                               float* __restrict__ C0,
                                               float* __restrict__ C1,
                                               int N, int K) {
  __shared__ __align__(16) float As[16][132];
  __shared__ __align__(16) float Ws[16][132];
  const float* W = blockIdx.y ? W1 : W0;
  float* C = blockIdx.y ? C1 : C0;
  const int bm = blockIdx.x * 128;
  const int tid = threadIdx.x;
  const int tm = (tid >> 4) * 8, tn = (tid & 15) * 8;
  float acc[8][8];
#pragma unroll
  for (int i = 0; i < 8; i++)
#pragma unroll
    for (int j = 0; j < 8; j++) acc[i][j] = 0.f;

  const int lr = tid >> 1, lk = (tid & 1) * 8;
  for (int k0 = 0; k0 < K; k0 += 16) {
    float4 a0 = *(const float4*)(A + (size_t)(bm + lr) * K + k0 + lk);
    float4 a1 = *(const float4*)(A + (size_t)(bm + lr) * K + k0 + lk + 4);
    float4 w0 = *(const float4*)(W + (size_t)(lr) * K + k0 + lk);
    float4 w1 = *(const float4*)(W + (size_t)(lr) * K + k0 + lk + 4);
    As[lk + 0][lr] = a0.x; As[lk + 1][lr] = a0.y; As[lk + 2][lr] = a0.z; As[lk + 3][lr] = a0.w;
    As[lk + 4][lr] = a1.x; As[lk + 5][lr] = a1.y; As[lk + 6][lr] = a1.z; As[lk + 7][lr] = a1.w;
    Ws[lk + 0][lr] = w0.x; Ws[lk + 1][lr] = w0.y; Ws[lk + 2][lr] = w0.z; Ws[lk + 3][lr] = w0.w;
    Ws[lk + 4][lr] = w1.x; Ws[lk + 5][lr] = w1.y; Ws[lk + 6][lr] = w1.z; Ws[lk + 7][lr] = w1.w;
    __syncthreads();
#pragma unroll
    for (int k = 0; k < 16; k++) {
      float4 av0 = *(const float4*)&As[k][tm];
      float4 av1 = *(const float4*)&As[k][tm + 4];
      float4 wv0 = *(const float4*)&Ws[k][tn];
      float4 wv1 = *(const float4*)&Ws[k][tn + 4];
      float a[8] = {av0.x, av0.y, av0.z, av0.w, av1.x, av1.y, av1.z, av1.w};
      float w[8] = {wv0.x, wv0.y, wv0.z, wv0.w, wv1.x, wv1.y, wv1.z, wv1.w};
#pragma unroll
      for (int i = 0; i < 8; i++)
#pragma unroll
        for (int j = 0; j < 8; j++) acc[i][j] += a[i] * w[j];
    }
    __syncthreads();
  }

#pragma unroll
  for (int i = 0; i < 8; i++) {
    float4 v0 = make_float4(acc[i][0], acc[i][1], acc[i][2], acc[i][3]);
    float4 v1 = make_float4(acc[i][4], acc[i][5], acc[i][6], acc[i][7]);
    *(float4*)(C + (size_t)(bm + tm + i) * N + tn) = v0;
    *(float4*)(C + (size_t)(bm + tm + i) * N + tn + 4) = v1;
  }
}

// ------------------------------------------------------------- LSTM layer ----
// Grid: 32 WGs = dir(2) x g(16), 512 threads (8 waves).
// Staging (R12 verbatim): ALL 8 waves poll 8 u64/lane (g-rotated offsets,
//   MALL agent protocol, stamp-validated), write hL[it&1].
// Compute (R14's verified mapping): waves 0-3, unit-major A-rows
//   (row=uoff*4+gate) so lane (quad,bcol) gets the 4 gates of unit
//   g*16+w8*4+quad, batch bcol, in acc[0..3] -> in-register nonlin,
//   no Lg LDS, and only ONE barrier per step (hL parity double-buffer).
// Hbuf entries: u64 {stamp=it+1, packed h}; relaxed agent-scope store.
__global__ __launch_bounds__(512) void k_lstm(const float* __restrict__ Gin,
                                              const float* __restrict__ whh,
                                              float* __restrict__ Houtf,
                                              unsigned int* __restrict__ Houtp,
                                              unsigned long long* __restrict__ Hbuf) {
  const int d = blockIdx.x >> 4;
  const int g = blockIdx.x & 15;
  const int tid = threadIdx.x;
  const int w8 = tid >> 6;         // all waves stage; waves 0-3 also compute
  const int lane = tid & 63;
  const int bcol = lane & 15;      // batch (A row-sel for weights / C col)
  const int quad = lane >> 4;
  const int ws = (w8 + g) & 7;     // rotated stage offset (spread bursts)
  __shared__ unsigned int hL[2][16 * 260];        // [parity][b*260 + k]

  // ---- one-time (waves 0-3): A fragments, unit-major rows ----
  // A row r = bcol: gate = r&3, unit_off = r>>2
  // whh row = d*1024 + gate*256 + g*16 + w8*4 + unit_off
  unsigned int Am[8][4], Ar[8][4];
  if (w8 < 4) {
    const float* wrow = whh + (size_t)((d << 10) + ((bcol & 3) << 8) + (g << 4) +
                                       (w8 << 2) + (bcol >> 2)) * 256;
#pragma unroll
    for (int s = 0; s < 8; ++s) {
      float w[8];
      *(float4*)&w[0] = *(const float4*)(wrow + s * 32 + quad * 8);
      *(float4*)&w[4] = *(const float4*)(wrow + s * 32 + quad * 8 + 4);
#pragma unroll
      for (int j = 0; j < 4; ++j) {
        unsigned short m0 = f2bf(w[2 * j]), m1 = f2bf(w[2 * j + 1]);
        unsigned short r0 = f2bf(w[2 * j] - bf2f(m0));
        unsigned short r1 = f2bf(w[2 * j + 1] - bf2f(m1));
        Am[s][j] = (unsigned)m0 | ((unsigned)m1 << 16);
        Ar[s][j] = (unsigned)r0 | ((unsigned)r1 << 16);
      }
    }
  }

  float c_reg = 0.f;
  for (int it = 0; it < 256; ++it) {
    const int step = d ? (255 - it) : it;

    // ---- Gin prefetch (compute lanes; independent of h) ----
    float gin[4];
    if (w8 < 4) {
#pragma unroll
      for (int qq = 0; qq < 4; ++qq)
        gin[qq] = Gin[((size_t)((step << 4) + bcol) << 11) + (d << 10) + (qq << 8) +
                      (g << 4) + (w8 << 2) + quad];
    }

    // ---- stage h_prev (R12 verbatim): 8 u64/lane, stamp-retry -> hL[it&1] ----
    if (it > 0) {
      const unsigned long long* src = Hbuf + ((size_t)((d << 1) + ((it - 1) & 1)) << 12);
      const unsigned long long* p0 = src + (ws << 9) + lane;
      const unsigned int want = (unsigned int)it;
      unsigned long long v[8];
#pragma unroll
      for (int c = 0; c < 8; ++c)
        v[c] = __hip_atomic_load(p0 + (c << 6), __ATOMIC_RELAXED, __HIP_MEMORY_SCOPE_AGENT);
      for (;;) {
        unsigned int badm = 0;
#pragma unroll
        for (int c = 0; c < 8; ++c)
          badm |= ((unsigned int)(v[c] >> 32) != want) ? (1u << c) : 0u;
        if (__ballot(badm != 0) == 0ull) break;
#pragma unroll
        for (int c = 0; c < 8; ++c)
          if (badm & (1u << c))
            v[c] = __hip_atomic_load(p0 + (c << 6), __ATOMIC_RELAXED, __HIP_MEMORY_SCOPE_AGENT);
      }
      unsigned int* hdst = hL[it & 1];
#pragma unroll
      for (int c = 0; c < 8; ++c) {
        int e_b = (ws << 1) + (c >> 2);            // entry e = ws*512+c*64+lane
        int e_k = ((c & 3) << 6) + lane;           //        = b*256+k
        hdst[e_b * 260 + e_k] = (unsigned int)v[c];
      }
    }
    __syncthreads();

    // ---- compute waves: MFMA from hL[it&1], in-register nonlin, publish ----
    if (w8 < 4) {
      f32x4 acc0 = {0.f, 0.f, 0.f, 0.f}, acc1 = acc0, acc2 = acc0;
      if (it > 0) {
        const unsigned int* hrow = &hL[it & 1][bcol * 260];
#pragma unroll
        for (int s = 0; s < 8; ++s) {
          const unsigned int* p = hrow + (s << 5) + (quad << 3);
          uint4 p0v = *(const uint4*)p;
          uint4 p1v = *(const uint4*)(p + 4);
          u32x4s8 Bm, Br, Amu, Aru;
          Bm.u[0] = __builtin_amdgcn_perm(p0v.y, p0v.x, 0x05040100u);
          Br.u[0] = __builtin_amdgcn_perm(p0v.y, p0v.x, 0x07060302u);
          Bm.u[1] = __builtin_amdgcn_perm(p0v.w, p0v.z, 0x05040100u);
          Br.u[1] = __builtin_amdgcn_perm(p0v.w, p0v.z, 0x07060302u);
          Bm.u[2] = __builtin_amdgcn_perm(p1v.y, p1v.x, 0x05040100u);
          Br.u[2] = __builtin_amdgcn_perm(p1v.y, p1v.x, 0x07060302u);
          Bm.u[3] = __builtin_amdgcn_perm(p1v.w, p1v.z, 0x05040100u);
          Br.u[3] = __builtin_amdgcn_perm(p1v.w, p1v.z, 0x07060302u);
#pragma unroll
          for (int j = 0; j < 4; ++j) { Amu.u[j] = Am[s][j]; Aru.u[j] = Ar[s][j]; }
          acc0 = __builtin_amdgcn_mfma_f32_16x16x32_bf16(Amu.v, Bm.v, acc0, 0, 0, 0);
          acc1 = __builtin_amdgcn_mfma_f32_16x16x32_bf16(Amu.v, Br.v, acc1, 0, 0, 0);
          acc2 = __builtin_amdgcn_mfma_f32_16x16x32_bf16(Aru.v, Bm.v, acc2, 0, 0, 0);
        }
      }
      f32x4 t = acc0 + acc1 + acc2;   // t[j] = gate j of (unit, batch)

      float gi = t[0] + gin[0];
      float gf = t[1] + gin[1];
      float gg = t[2] + gin[2];
      float go = t[3] + gin[3];
      float ct = sigm(gf) * c_reg + sigm(gi) * tanh_fast(gg);
      c_reg = ct;
      float h = sigm(go) * tanh_fast(ct);
      unsigned short hm = f2bf(h);
      unsigned short hr = f2bf(h - bf2f(hm));
      unsigned int hpk = ((unsigned)hr << 16) | (unsigned)hm;
      unsigned long long hp = ((unsigned long long)(unsigned int)(it + 1) << 32) |
                              (unsigned long long)hpk;
      __hip_atomic_store(Hbuf + ((size_t)((d << 1) + (it & 1)) << 12) +
                         (bcol << 8) + (g << 4) + (w8 << 2) + quad,
                         hp, __ATOMIC_RELAXED, __HIP_MEMORY_SCOPE_AGENT);
      size_t oidx = (size_t)((step << 4) + bcol) * 512 + (d << 8) + (g << 4) +
                    (w8 << 2) + quad;
      Houtf[oidx] = h;
      Houtp[oidx] = hpk;
    }
    // no drain barrier: stagers validate stamps themselves.
  }
}

// ------------------------------------------------------------- attention ----
// scores[b][i][j] = sum_h va[h]*tanh(P[i*16+b][h] + Cc[j*16+b][h])
// out[0 .. 1M) = scores; out[1M .. 2M) = predictions (sigmoid>=0.5 <=> x>=0)
__global__ __launch_bounds__(256) void k_attn(const float* __restrict__ P,
                                              const float* __restrict__ Cc,
                                              const float* __restrict__ va,
                                              float* __restrict__ out) {
  const int b = blockIdx.x & 15, i = blockIdx.x >> 4;
  __shared__ float pv[128], vv[128];
  const int t = threadIdx.x;
  if (t < 128) {
    pv[t] = P[(size_t)((i << 4) + b) * 128 + t];
    vv[t] = va[t];
  }
  __syncthreads();
  const float4* c4 = reinterpret_cast<const float4*>(Cc + (size_t)((t << 4) + b) * 128);
  float acc = 0.f;
#pragma unroll 8
  for (int hh = 0; hh < 32; ++hh) {
    float4 cv = c4[hh];
    int h = hh << 2;
    acc += vv[h]     * tanh_fast(pv[h]     + cv.x);
    acc += vv[h + 1] * tanh_fast(pv[h + 1] + cv.y);
    acc += vv[h + 2] * tanh_fast(pv[h + 2] + cv.z);
    acc += vv[h + 3] * tanh_fast(pv[h + 3] + cv.w);
  }
  size_t o = ((size_t)b << 16) + ((size_t)i << 8) + (size_t)t;
  out[o] = acc;
  out[(1u << 20) + o] = (acc >= 0.f) ? 1.f : 0.f;
}

// --------------------------------------------------------------- launch ----
extern "C" void kernel_launch(void* const* d_in, const int* in_sizes, int n_in,
                              void* d_out, int out_size, void* d_ws, size_t ws_size,
                              hipStream_t stream) {
  const int*   concepts = (const int*)d_in[0];
  // d_in[1] = concepts_lengths (all == S, unused)
  const float* emb  = (const float*)d_in[2];
  const float* w_ih = (const float*)d_in[3];   // [2][2][1024][512]
  const float* w_hh = (const float*)d_in[4];   // [2][2][1024][256]
  const float* bias = (const float*)d_in[5];   // [2][2][1024]
  const float* Ua   = (const float*)d_in[6];   // [128][512]
  const float* Wa   = (const float*)d_in[7];   // [128][512]
  const float* va   = (const float*)d_in[8];   // [1][128]
  float* out = (float*)d_out;
  float* ws  = (float*)d_ws;

  // workspace (floats) — total 15,794,176 floats = byte-identical to R4 usage
  constexpr size_t OFF_G   = 0;                               // [4096][2048] f32
  constexpr size_t OFF_PK  = OFF_G  + (size_t)M_ * 2048;      // Xpk/H0pk/H1pk u32 [4096][512]
  constexpr size_t OFF_WPK = OFF_PK + (size_t)M_ * 512;       // Wpk u32 [2][2048][512]
  constexpr size_t OFF_HF  = OFF_WPK + 2 * 2048 * 512;        // H f32 [4096][512]
  constexpr size_t OFF_P   = OFF_HF + (size_t)M_ * 512;       // Pm [4096][128]
  constexpr size_t OFF_C   = OFF_P  + (size_t)M_ * HM_;       // Cm [4096][128]
  constexpr size_t OFF_HB  = OFF_C  + (size_t)M_ * HM_;       // Hbuf u64 x2 layers

  float* G  = ws + OFF_G;
  unsigned int* PK  = (unsigned int*)(ws + OFF_PK);
  unsigned int* WPK = (unsigned int*)(ws + OFF_WPK);
  float* HF = ws + OFF_HF;
  float* Pm = ws + OFF_P;
  float* Cm = ws + OFF_C;
  unsigned long long* Hb0 = (unsigned long long*)(ws + OFF_HB);
  unsigned long long* Hb1 = Hb0 + 2 * 2 * 4096;

  // fused: pack w_ih (both layers) + gather/pack X + zero Hbuf stamps
  constexpr int NPACK = 2 * 2048 * 512 / 4 / 256;   // 2048 blocks
  k_prep<<<NPACK + M_, 256, 0, stream>>>(w_ih, WPK, 2 * 2048 * 512 / 4, NPACK,
                                         concepts, emb, PK, Hb0);

  // layer 0: Gin GEMM (MFMA split-bf16) then recurrence (writes H0 packed into PK)
  k_gemm_pk<<<dim3(32, 16), 256, 0, stream>>>(PK, WPK, bias, G, 2048, 512);
  k_lstm<<<32, 512, 0, stream>>>(G, w_hh, HF, PK, Hb0);   // PK now = H0pk (Xpk dead)

  // layer 1
  k_gemm_pk<<<dim3(32, 16), 256, 0, stream>>>(PK, WPK + (size_t)2048 * 512, bias + 2048,
                                              G, 2048, 512);
  k_lstm<<<32, 512, 0, stream>>>(G, w_hh + (size_t)2048 * 256, HF, PK, Hb1);  // HF = H1 f32

  // attention projections (fp32; small) — both in ONE launch
  k_gemm2<<<dim3(32, 2), 256, 0, stream>>>(HF, Ua, Wa, Pm, Cm, HM_, 512);

  // fused pairwise scores + predictions
  k_attn<<<M_, 256, 0, stream>>>(Pm, Cm, va, out);
}

// Round 9
// 1488.990 us; speedup vs baseline: 1.4419x; 1.2241x over previous
//
#include <hip/hip_runtime.h>

// ---------------------------------------------------------------------------
// HeadsSelection: emb-gather -> 2x bidirectional LSTM -> additive attention
// S=256, B=16, V=20000, E=512, H=256, L=2, HM=128
// Round 16: strict revert to R12's k_lstm (best measured: 597us/layer,
// total 1491us) + keep only launch-level wins.
//   R15 post-mortem: unit-major ownership fragmented the publish stores
//   (16x32B vs R12's 4x128B per wave) -> MALL store queueing -> +0.68us/step
//   (FETCH 100->111MB = more stale rounds). R12's Lg round-trip BUYS the
//   coalesced publish; in-register nonlin is net-negative. Combined with
//   R13 (pipelined poll, -17%) and R14 (wave specialization, -62%), every
//   perturbation of the R12 exchange regresses -> R12 k_lstm restored
//   bit-for-bit.
//   Kept: k_prep fusion (pack w_ih + gather X + zero Hbuf stamps in ONE
//   launch; independent of k_lstm) and merged k_gemm2 projections.
// ---------------------------------------------------------------------------

#define S_    256
#define B_    16
#define E_    512
#define H_    256
#define HM_   128
#define M_    4096   // S*B

typedef __attribute__((ext_vector_type(8))) short short8;
typedef __attribute__((ext_vector_type(4))) float f32x4;
union u32x4s8 { unsigned int u[4]; uint4 u4; short8 v; };

__device__ __forceinline__ float sigm(float x) { return 1.f / (1.f + __expf(-x)); }
__device__ __forceinline__ float tanh_fast(float x) {
  x = fminf(fmaxf(x, -15.f), 15.f);
  float e = __expf(2.f * x);
  return (e - 1.f) / (e + 1.f);
}
__device__ __forceinline__ unsigned short f2bf(float f) {
  unsigned u = __float_as_uint(f);
  u += 0x7FFFu + ((u >> 16) & 1u);
  return (unsigned short)(u >> 16);
}
__device__ __forceinline__ float bf2f(unsigned short s) {
  return __uint_as_float(((unsigned)s) << 16);
}
// pack float -> {low16: main bf16, high16: residual bf16}
__device__ __forceinline__ unsigned int packsplit(float f) {
  unsigned short m = f2bf(f);
  unsigned short r = f2bf(f - bf2f(m));
  return (unsigned)m | ((unsigned)r << 16);
}

// ----------------------------------------------------- fused pack+gather ----
// blocks [0, npack): pack w_ih float->split-bf16 u32 (4 floats/thread).
// blocks [npack, npack+4096): gather emb rows -> Xpk packed; also zero the
// Hbuf stamp region (4096 blocks x 8 u64 = both layers' stamp buffers).
__global__ void k_prep(const float* __restrict__ w_ih, unsigned int* __restrict__ WPK,
                       int n4, int npack,
                       const int* __restrict__ concepts, const float* __restrict__ emb,
                       unsigned int* __restrict__ Xpk,
                       unsigned long long* __restrict__ hbz) {
  if (blockIdx.x < (unsigned)npack) {
    int i = blockIdx.x * blockDim.x + threadIdx.x;
    if (i < n4) {
      float4 v = reinterpret_cast<const float4*>(w_ih)[i];
      uint4 o;
      o.x = packsplit(v.x); o.y = packsplit(v.y); o.z = packsplit(v.z); o.w = packsplit(v.w);
      reinterpret_cast<uint4*>(WPK)[i] = o;
    }
    return;
  }
  int m = blockIdx.x - npack;               // m = s*16 + b
  if (threadIdx.x < 8)
    hbz[(size_t)m * 8 + threadIdx.x] = 0ull;
  int tok = concepts[m];
  const float4* src = reinterpret_cast<const float4*>(emb + (size_t)tok * E_);
  uint4* dst = reinterpret_cast<uint4*>(Xpk + (size_t)m * E_);
  for (int i = threadIdx.x; i < E_ / 4; i += blockDim.x) {
    float4 v = src[i];
    uint4 o;
    o.x = packsplit(v.x); o.y = packsplit(v.y); o.z = packsplit(v.z); o.w = packsplit(v.w);
    dst[i] = o;
  }
}

// ------------------------------------------------------------- MFMA GEMM ----
// C[m][n] = sum_k A[m][k]*W[n][k] + bias[n], A/W packed split-bf16 u32.
// 3-product scheme: Am*Bm + Am*Br + Ar*Bm (~2^-17 rel err).
// WG = 128x128 tile, 4 waves in 2x2, wave = 64x64 (4x4 MFMA 16x16x32 tiles).
__global__ __launch_bounds__(256) void k_gemm_pk(const unsigned int* __restrict__ Apk,
                                                 const unsigned int* __restrict__ Wpk,
                                                 const float* __restrict__ bias,
                                                 float* __restrict__ C, int N, int K) {
  __shared__ unsigned int As[128][36];
  __shared__ unsigned int Ws2[128][36];
  const int bm = blockIdx.x * 128, bn = blockIdx.y * 128;
  const int tid = threadIdx.x;
  const int wave = tid >> 6, lane = tid & 63;
  const int wm = (wave >> 1) << 6, wn = (wave & 1) << 6;
  const int l16 = lane & 15, quad = lane >> 4;
  const int r = tid >> 1, cb = (tid & 1) << 4;

  f32x4 acc[4][4];
#pragma unroll
  for (int i = 0; i < 4; ++i)
#pragma unroll
    for (int j = 0; j < 4; ++j) acc[i][j] = (f32x4){0.f, 0.f, 0.f, 0.f};

  for (int k0 = 0; k0 < K; k0 += 32) {
    const unsigned int* pa = Apk + (size_t)(bm + r) * K + k0 + cb;
    const unsigned int* pw = Wpk + (size_t)(bn + r) * K + k0 + cb;
    uint4 a0 = *(const uint4*)pa, a1 = *(const uint4*)(pa + 4),
          a2 = *(const uint4*)(pa + 8), a3 = *(const uint4*)(pa + 12);
    uint4 w0 = *(const uint4*)pw, w1 = *(const uint4*)(pw + 4),
          w2 = *(const uint4*)(pw + 8), w3 = *(const uint4*)(pw + 12);
    __syncthreads();                         // previous iter's frag reads done
    *(uint4*)&As[r][cb] = a0;  *(uint4*)&As[r][cb + 4] = a1;
    *(uint4*)&As[r][cb + 8] = a2; *(uint4*)&As[r][cb + 12] = a3;
    *(uint4*)&Ws2[r][cb] = w0; *(uint4*)&Ws2[r][cb + 4] = w1;
    *(uint4*)&Ws2[r][cb + 8] = w2; *(uint4*)&Ws2[r][cb + 12] = w3;
    __syncthreads();

    short8 Amv[4], Arv[4], Bmv[4], Brv[4];
#pragma unroll
    for (int t = 0; t < 4; ++t) {
      const unsigned int* p = &As[wm + (t << 4) + l16][quad << 3];
      uint4 p0 = *(const uint4*)p, p1 = *(const uint4*)(p + 4);
      u32x4s8 m, rr;
      m.u[0] = __builtin_amdgcn_perm(p0.y, p0.x, 0x05040100u);
      rr.u[0] = __builtin_amdgcn_perm(p0.y, p0.x, 0x07060302u);
      m.u[1] = __builtin_amdgcn_perm(p0.w, p0.z, 0x05040100u);
      rr.u[1] = __builtin_amdgcn_perm(p0.w, p0.z, 0x07060302u);
      m.u[2] = __builtin_amdgcn_perm(p1.y, p1.x, 0x05040100u);
      rr.u[2] = __builtin_amdgcn_perm(p1.y, p1.x, 0x07060302u);
      m.u[3] = __builtin_amdgcn_perm(p1.w, p1.z, 0x05040100u);
      rr.u[3] = __builtin_amdgcn_perm(p1.w, p1.z, 0x07060302u);
      Amv[t] = m.v; Arv[t] = rr.v;
      const unsigned int* pb = &Ws2[wn + (t << 4) + l16][quad << 3];
      uint4 q0 = *(const uint4*)pb, q1 = *(const uint4*)(pb + 4);
      m.u[0] = __builtin_amdgcn_perm(q0.y, q0.x, 0x05040100u);
      rr.u[0] = __builtin_amdgcn_perm(q0.y, q0.x, 0x07060302u);
      m.u[1] = __builtin_amdgcn_perm(q0.w, q0.z, 0x05040100u);
      rr.u[1] = __builtin_amdgcn_perm(q0.w, q0.z, 0x07060302u);
      m.u[2] = __builtin_amdgcn_perm(q1.y, q1.x, 0x05040100u);
      rr.u[2] = __builtin_amdgcn_perm(q1.y, q1.x, 0x07060302u);
      m.u[3] = __builtin_amdgcn_perm(q1.w, q1.z, 0x05040100u);
      rr.u[3] = __builtin_amdgcn_perm(q1.w, q1.z, 0x07060302u);
      Bmv[t] = m.v; Brv[t] = rr.v;
    }
#pragma unroll
    for (int ti = 0; ti < 4; ++ti)
#pragma unroll
      for (int tj = 0; tj < 4; ++tj) {
        acc[ti][tj] = __builtin_amdgcn_mfma_f32_16x16x32_bf16(Amv[ti], Bmv[tj], acc[ti][tj], 0, 0, 0);
        acc[ti][tj] = __builtin_amdgcn_mfma_f32_16x16x32_bf16(Amv[ti], Brv[tj], acc[ti][tj], 0, 0, 0);
        acc[ti][tj] = __builtin_amdgcn_mfma_f32_16x16x32_bf16(Arv[ti], Bmv[tj], acc[ti][tj], 0, 0, 0);
      }
  }

  float bv[4];
#pragma unroll
  for (int tj = 0; tj < 4; ++tj)
    bv[tj] = bias ? bias[bn + wn + (tj << 4) + l16] : 0.f;
#pragma unroll
  for (int ti = 0; ti < 4; ++ti)
#pragma unroll
    for (int rr = 0; rr < 4; ++rr) {
      float* crow = C + (size_t)(bm + wm + (ti << 4) + (quad << 2) + rr) * N + bn + wn + l16;
      crow[0]  = acc[ti][0][rr] + bv[0];
      crow[16] = acc[ti][1][rr] + bv[1];
      crow[32] = acc[ti][2][rr] + bv[2];
      crow[48] = acc[ti][3][rr] + bv[3];
    }
}

// ------------------------------------------------------------- fp32 GEMM ----
// merged projections: blockIdx.y==0 -> C0 = A @ W0^T (Ua->Pm),
//                     blockIdx.y==1 -> C1 = A @ W1^T (Wa->Cm).
// Per-block arithmetic identical to the original single-GEMM kernel
// (bn=0, N=128) => bit-identical outputs, but both run concurrently.
__global__ __launch_bounds__(256) void k_gemm2(const float* __restrict__ A,
                                               const float* __restrict__ W0,
                                               const float* __restrict__ W1,
                                               float* __restrict__ C0,
                                               float* __restrict__ C1,
                                               int N, int K) {
  __shared__ __align__(16) float As[16][132];
  __shared__ __align__(16) float Ws[16][132];
  const float* W = blockIdx.y ? W1 : W0;
  float* C = blockIdx.y ? C1 : C0;
  const int bm = blockIdx.x * 128;
  const int tid = threadIdx.x;
  const int tm = (tid >> 4) * 8, tn = (tid & 15) * 8;
  float acc[8][8];
#pragma unroll
  for (int i = 0; i < 8; i++)
#pragma unroll
    for (int j = 0; j < 8; j++) acc[i][j] = 0.f;

  const int lr = tid >> 1, lk = (tid & 1) * 8;
  for (int k0 = 0; k0 < K; k0 += 16) {
    float4 a0 = *(const float4*)(A + (size_t)(bm + lr) * K + k0 + lk);
    float4 a1 = *(const float4*)(A + (size_t)(bm + lr) * K + k0 + lk + 4);
    float4 w0 = *(const float4*)(W + (size_t)(lr) * K + k0 + lk);
    float4 w1 = *(const float4*)(W + (size_t)(lr) * K + k0 + lk + 4);
    As[lk + 0][lr] = a0.x; As[lk + 1][lr] = a0.y; As[lk + 2][lr] = a0.z; As[lk + 3][lr] = a0.w;
    As[lk + 4][lr] = a1.x; As[lk + 5][lr] = a1.y; As[lk + 6][lr] = a1.z; As[lk + 7][lr] = a1.w;
    Ws[lk + 0][lr] = w0.x; Ws[lk + 1][lr] = w0.y; Ws[lk + 2][lr] = w0.z; Ws[lk + 3][lr] = w0.w;
    Ws[lk + 4][lr] = w1.x; Ws[lk + 5][lr] = w1.y; Ws[lk + 6][lr] = w1.z; Ws[lk + 7][lr] = w1.w;
    __syncthreads();
#pragma unroll
    for (int k = 0; k < 16; k++) {
      float4 av0 = *(const float4*)&As[k][tm];
      float4 av1 = *(const float4*)&As[k][tm + 4];
      float4 wv0 = *(const float4*)&Ws[k][tn];
      float4 wv1 = *(const float4*)&Ws[k][tn + 4];
      float a[8] = {av0.x, av0.y, av0.z, av0.w, av1.x, av1.y, av1.z, av1.w};
      float w[8] = {wv0.x, wv0.y, wv0.z, wv0.w, wv1.x, wv1.y, wv1.z, wv1.w};
#pragma unroll
      for (int i = 0; i < 8; i++)
#pragma unroll
        for (int j = 0; j < 8; j++) acc[i][j] += a[i] * w[j];
    }
    __syncthreads();
  }

#pragma unroll
  for (int i = 0; i < 8; i++) {
    float4 v0 = make_float4(acc[i][0], acc[i][1], acc[i][2], acc[i][3]);
    float4 v1 = make_float4(acc[i][4], acc[i][5], acc[i][6], acc[i][7]);
    *(float4*)(C + (size_t)(bm + tm + i) * N + tn) = v0;
    *(float4*)(C + (size_t)(bm + tm + i) * N + tn + 4) = v1;
  }
}

// ------------------------------------------------------------- LSTM layer ----
// R12 VERBATIM (best measured). Grid: 32 WGs = dir(2) x g(16), 512 threads
// (8 waves). Waves 0-3: gate q MFMA (16x16x32 split-bf16 3-product, K=256).
// All 8 waves stage h_prev: 8 u64 loads/lane per poll round, wave-rotated
// offsets. Hbuf entries are u64 {stamp=it+1, packed h}; single relaxed
// agent-scope store publishes; consumers stamp-validate (no fences).
// Gin: [m][2048] row-major. Houtf: [m][512] f32. Houtp: same idx packed u32.
__global__ __launch_bounds__(512) void k_lstm(const float* __restrict__ Gin,
                                              const float* __restrict__ whh,
                                              float* __restrict__ Houtf,
                                              unsigned int* __restrict__ Houtp,
                                              unsigned long long* __restrict__ Hbuf) {
  const int d = blockIdx.x >> 4;
  const int g = blockIdx.x & 15;
  const int tid = threadIdx.x;
  const int w8 = tid >> 6;         // wave 0..7; waves 0-3 also run MFMA (gate q=w8)
  const int lane = tid & 63;
  const int bcol = lane & 15;      // MFMA A row / C col (batch)
  const int quad = lane >> 4;      // MFMA k-group / C row group
  const int u_e = tid & 15;        // epilogue (tid<256): unit
  const int b_e = (tid >> 4) & 15; // epilogue: batch
  const int ws = (w8 + g) & 7;     // rotated stage offset (spread bursts)
  __shared__ unsigned int hL[16 * 260];           // packed h: [b]*260 + [k]
  __shared__ __align__(16) float Lg[4][16][24];   // [gate][b][unit(+pad)]

  // ---- one-time: A fragments (whh) into VGPRs, split bf16 main+residual ----
  unsigned int Am[8][4], Ar[8][4];
  if (w8 < 4) {
    const float* wrow = whh + (size_t)((d << 10) + (w8 << 8) + (g << 4) + bcol) * 256;
#pragma unroll
    for (int s = 0; s < 8; ++s) {
      float w[8];
      *(float4*)&w[0] = *(const float4*)(wrow + s * 32 + quad * 8);
      *(float4*)&w[4] = *(const float4*)(wrow + s * 32 + quad * 8 + 4);
#pragma unroll
      for (int j = 0; j < 4; ++j) {
        unsigned short m0 = f2bf(w[2 * j]), m1 = f2bf(w[2 * j + 1]);
        unsigned short r0 = f2bf(w[2 * j] - bf2f(m0));
        unsigned short r1 = f2bf(w[2 * j + 1] - bf2f(m1));
        Am[s][j] = (unsigned)m0 | ((unsigned)m1 << 16);
        Ar[s][j] = (unsigned)r0 | ((unsigned)r1 << 16);
      }
    }
  }

  float c_reg = 0.f;
  for (int it = 0; it < 256; ++it) {
    const int step = d ? (255 - it) : it;

    // ---- Gin prefetch (independent of h; row-major coalesced) ----
    float gin[4];
    if (tid < 256) {
#pragma unroll
      for (int qq = 0; qq < 4; ++qq)
        gin[qq] = Gin[((size_t)((step << 4) + b_e) << 11) + (d << 10) + (qq << 8) + (g << 4) + u_e];
    }

    // ---- stage h_prev: 8 u64 loads/lane, stamp-retry, write LDS ----
    if (it > 0) {
      const unsigned long long* src = Hbuf + ((size_t)((d << 1) + ((it - 1) & 1)) << 12);
      const unsigned long long* p0 = src + (ws << 9) + lane;
      const unsigned int want = (unsigned int)it;
      unsigned long long v[8];
#pragma unroll
      for (int c = 0; c < 8; ++c)
        v[c] = __hip_atomic_load(p0 + (c << 6), __ATOMIC_RELAXED, __HIP_MEMORY_SCOPE_AGENT);
      for (;;) {
        unsigned int badm = 0;
#pragma unroll
        for (int c = 0; c < 8; ++c)
          badm |= ((unsigned int)(v[c] >> 32) != want) ? (1u << c) : 0u;
        if (__ballot(badm != 0) == 0ull) break;
#pragma unroll
        for (int c = 0; c < 8; ++c)
          if (badm & (1u << c))
            v[c] = __hip_atomic_load(p0 + (c << 6), __ATOMIC_RELAXED, __HIP_MEMORY_SCOPE_AGENT);
      }
#pragma unroll
      for (int c = 0; c < 8; ++c) {
        int e_b = (ws << 1) + (c >> 2);            // entry e = ws*512+c*64+lane
        int e_k = ((c & 3) << 6) + lane;           //        = b*256+k
        hL[e_b * 260 + e_k] = (unsigned int)v[c];
      }
    }
    __syncthreads();

    // ---- B fragments from LDS, 3-product split MFMA (waves 0-3) ----
    if (w8 < 4) {
      f32x4 acc0 = {0.f, 0.f, 0.f, 0.f}, acc1 = acc0, acc2 = acc0;
      if (it > 0) {
#pragma unroll
        for (int s = 0; s < 8; ++s) {
          const unsigned int* p = &hL[bcol * 260 + (s << 5) + (quad << 3)];
          uint4 p0v = *(const uint4*)p;
          uint4 p1v = *(const uint4*)(p + 4);
          u32x4s8 Bm, Br, Amu, Aru;
          Bm.u[0] = __builtin_amdgcn_perm(p0v.y, p0v.x, 0x05040100u);
          Br.u[0] = __builtin_amdgcn_perm(p0v.y, p0v.x, 0x07060302u);
          Bm.u[1] = __builtin_amdgcn_perm(p0v.w, p0v.z, 0x05040100u);
          Br.u[1] = __builtin_amdgcn_perm(p0v.w, p0v.z, 0x07060302u);
          Bm.u[2] = __builtin_amdgcn_perm(p1v.y, p1v.x, 0x05040100u);
          Br.u[2] = __builtin_amdgcn_perm(p1v.y, p1v.x, 0x07060302u);
          Bm.u[3] = __builtin_amdgcn_perm(p1v.w, p1v.z, 0x05040100u);
          Br.u[3] = __builtin_amdgcn_perm(p1v.w, p1v.z, 0x07060302u);
#pragma unroll
          for (int j = 0; j < 4; ++j) { Amu.u[j] = Am[s][j]; Aru.u[j] = Ar[s][j]; }
          acc0 = __builtin_amdgcn_mfma_f32_16x16x32_bf16(Amu.v, Bm.v, acc0, 0, 0, 0);
          acc1 = __builtin_amdgcn_mfma_f32_16x16x32_bf16(Amu.v, Br.v, acc1, 0, 0, 0);
          acc2 = __builtin_amdgcn_mfma_f32_16x16x32_bf16(Aru.v, Bm.v, acc2, 0, 0, 0);
        }
      }
      f32x4 t = acc0 + acc1 + acc2;
      *(float4*)&Lg[w8][bcol][quad << 2] = make_float4(t[0], t[1], t[2], t[3]);
    }
    __syncthreads();

    // ---- nonlinearity + state update; fire-and-forget publish ----
    if (tid < 256) {
      float gi = Lg[0][b_e][u_e] + gin[0];
      float gf = Lg[1][b_e][u_e] + gin[1];
      float gg = Lg[2][b_e][u_e] + gin[2];
      float go = Lg[3][b_e][u_e] + gin[3];
      float ct = sigm(gf) * c_reg + sigm(gi) * tanh_fast(gg);
      c_reg = ct;
      float h = sigm(go) * tanh_fast(ct);
      unsigned short hm = f2bf(h);
      unsigned short hr = f2bf(h - bf2f(hm));
      unsigned int hpk = ((unsigned)hr << 16) | (unsigned)hm;
      unsigned long long hp = ((unsigned long long)(unsigned int)(it + 1) << 32) |
                              (unsigned long long)hpk;
      __hip_atomic_store(Hbuf + ((size_t)((d << 1) + (it & 1)) << 12) + (b_e << 8) + (g << 4) + u_e,
                         hp, __ATOMIC_RELAXED, __HIP_MEMORY_SCOPE_AGENT);
      size_t oidx = (size_t)((step << 4) + b_e) * 512 + (d << 8) + (g << 4) + u_e;
      Houtf[oidx] = h;
      Houtp[oidx] = hpk;
    }
    // no drain barrier: consumers validate stamps themselves.
  }
}

// ------------------------------------------------------------- attention ----
// scores[b][i][j] = sum_h va[h]*tanh(P[i*16+b][h] + Cc[j*16+b][h])
// out[0 .. 1M) = scores; out[1M .. 2M) = predictions (sigmoid>=0.5 <=> x>=0)
__global__ __launch_bounds__(256) void k_attn(const float* __restrict__ P,
                                              const float* __restrict__ Cc,
                                              const float* __restrict__ va,
                                              float* __restrict__ out) {
  const int b = blockIdx.x & 15, i = blockIdx.x >> 4;
  __shared__ float pv[128], vv[128];
  const int t = threadIdx.x;
  if (t < 128) {
    pv[t] = P[(size_t)((i << 4) + b) * 128 + t];
    vv[t] = va[t];
  }
  __syncthreads();
  const float4* c4 = reinterpret_cast<const float4*>(Cc + (size_t)((t << 4) + b) * 128);
  float acc = 0.f;
#pragma unroll 8
  for (int hh = 0; hh < 32; ++hh) {
    float4 cv = c4[hh];
    int h = hh << 2;
    acc += vv[h]     * tanh_fast(pv[h]     + cv.x);
    acc += vv[h + 1] * tanh_fast(pv[h + 1] + cv.y);
    acc += vv[h + 2] * tanh_fast(pv[h + 2] + cv.z);
    acc += vv[h + 3] * tanh_fast(pv[h + 3] + cv.w);
  }
  size_t o = ((size_t)b << 16) + ((size_t)i << 8) + (size_t)t;
  out[o] = acc;
  out[(1u << 20) + o] = (acc >= 0.f) ? 1.f : 0.f;
}

// --------------------------------------------------------------- launch ----
extern "C" void kernel_launch(void* const* d_in, const int* in_sizes, int n_in,
                              void* d_out, int out_size, void* d_ws, size_t ws_size,
                              hipStream_t stream) {
  const int*   concepts = (const int*)d_in[0];
  // d_in[1] = concepts_lengths (all == S, unused)
  const float* emb  = (const float*)d_in[2];
  const float* w_ih = (const float*)d_in[3];   // [2][2][1024][512]
  const float* w_hh = (const float*)d_in[4];   // [2][2][1024][256]
  const float* bias = (const float*)d_in[5];   // [2][2][1024]
  const float* Ua   = (const float*)d_in[6];   // [128][512]
  const float* Wa   = (const float*)d_in[7];   // [128][512]
  const float* va   = (const float*)d_in[8];   // [1][128]
  float* out = (float*)d_out;
  float* ws  = (float*)d_ws;

  // workspace (floats) — total 15,794,176 floats = byte-identical to R4 usage
  constexpr size_t OFF_G   = 0;                               // [4096][2048] f32
  constexpr size_t OFF_PK  = OFF_G  + (size_t)M_ * 2048;      // Xpk/H0pk/H1pk u32 [4096][512]
  constexpr size_t OFF_WPK = OFF_PK + (size_t)M_ * 512;       // Wpk u32 [2][2048][512]
  constexpr size_t OFF_HF  = OFF_WPK + 2 * 2048 * 512;        // H f32 [4096][512]
  constexpr size_t OFF_P   = OFF_HF + (size_t)M_ * 512;       // Pm [4096][128]
  constexpr size_t OFF_C   = OFF_P  + (size_t)M_ * HM_;       // Cm [4096][128]
  constexpr size_t OFF_HB  = OFF_C  + (size_t)M_ * HM_;       // Hbuf u64 x2 layers

  float* G  = ws + OFF_G;
  unsigned int* PK  = (unsigned int*)(ws + OFF_PK);
  unsigned int* WPK = (unsigned int*)(ws + OFF_WPK);
  float* HF = ws + OFF_HF;
  float* Pm = ws + OFF_P;
  float* Cm = ws + OFF_C;
  unsigned long long* Hb0 = (unsigned long long*)(ws + OFF_HB);
  unsigned long long* Hb1 = Hb0 + 2 * 2 * 4096;

  // fused: pack w_ih (both layers) + gather/pack X + zero Hbuf stamps
  constexpr int NPACK = 2 * 2048 * 512 / 4 / 256;   // 2048 blocks
  k_prep<<<NPACK + M_, 256, 0, stream>>>(w_ih, WPK, 2 * 2048 * 512 / 4, NPACK,
                                         concepts, emb, PK, Hb0);

  // layer 0: Gin GEMM (MFMA split-bf16) then recurrence (writes H0 packed into PK)
  k_gemm_pk<<<dim3(32, 16), 256, 0, stream>>>(PK, WPK, bias, G, 2048, 512);
  k_lstm<<<32, 512, 0, stream>>>(G, w_hh, HF, PK, Hb0);   // PK now = H0pk (Xpk dead)

  // layer 1
  k_gemm_pk<<<dim3(32, 16), 256, 0, stream>>>(PK, WPK + (size_t)2048 * 512, bias + 2048,
                                              G, 2048, 512);
  k_lstm<<<32, 512, 0, stream>>>(G, w_hh + (size_t)2048 * 256, HF, PK, Hb1);  // HF = H1 f32

  // attention projections (fp32; small) — both in ONE launch, bit-identical
  // per-block arithmetic to the previous two back-to-back k_gemm calls.
  k_gemm2<<<dim3(32, 2), 256, 0, stream>>>(HF, Ua, Wa, Pm, Cm, HM_, 512);

  // fused pairwise scores + predictions
  k_attn<<<M_, 256, 0, stream>>>(Pm, Cm, va, out);
}